// Round 5
// baseline (2425.640 us; speedup 1.0000x reference)
//
#include <hip/hip_runtime.h>

#define NHEADS 8
#define DIM 384
#define BB 4
#define HW 16384      // 128*128
#define CPH 48        // channels per head

typedef unsigned int u32;
typedef __attribute__((ext_vector_type(8))) short bf16x8;
typedef __attribute__((ext_vector_type(4))) float f32x4;

__device__ __forceinline__ float b2f(unsigned short u) {
    union { u32 i; float f; } x; x.i = ((u32)u) << 16; return x.f;
}
__device__ __forceinline__ unsigned short f2b(float f) {
    u32 x = __float_as_uint(f);
    u32 r = (x + 0x7fffu + ((x >> 16) & 1u)) >> 16;   // RNE
    return (unsigned short)r;
}

// async global->LDS, 16B per lane; LDS dest = wave-uniform base + lane*16
#define GLOBAL_TO_LDS16(gsrc, ldst)                                           \
    __builtin_amdgcn_global_load_lds(                                         \
        (const __attribute__((address_space(1))) u32*)(gsrc),                 \
        (__attribute__((address_space(3))) u32*)(ldst), 16, 0, 0)

// ---------------- fp32 -> bf16 hi/lo split (weights) ----------------
__global__ void cvt_w(const float* __restrict__ a,
                      unsigned short* __restrict__ hi, unsigned short* __restrict__ lo, int n)
{
    const int i = blockIdx.x * 256 + threadIdx.x;
    if (i < n) {
        const float v = a[i];
        const unsigned short h = f2b(v);
        hi[i] = h;
        lo[i] = f2b(v - b2f(h));
    }
}

// ---------------- x[b][c][n] fp32 -> xt_hi/xt_lo[b][n][c] bf16 ----------------
__global__ __launch_bounds__(256) void transpose_cvt(
    const float* __restrict__ x,
    unsigned short* __restrict__ xth, unsigned short* __restrict__ xtl)
{
    const int n  = blockIdx.x * 256 + threadIdx.x;
    const int c0 = blockIdx.y * 16;
    const int b  = blockIdx.z;
    const float* xp = x + ((size_t)b * DIM + c0) * HW + n;
    alignas(16) unsigned short th[16];
    alignas(16) unsigned short tl[16];
    #pragma unroll
    for (int j = 0; j < 16; ++j) {
        const float v = xp[(size_t)j * HW];
        const unsigned short h = f2b(v);
        th[j] = h;
        tl[j] = f2b(v - b2f(h));
    }
    unsigned short* oh = xth + ((size_t)b * HW + n) * DIM + c0;
    unsigned short* ol = xtl + ((size_t)b * HW + n) * DIM + c0;
    *(uint4*)&oh[0] = *(const uint4*)&th[0];
    *(uint4*)&oh[8] = *(const uint4*)&th[8];
    *(uint4*)&ol[0] = *(const uint4*)&tl[0];
    *(uint4*)&ol[8] = *(const uint4*)&tl[8];
}

// ---------------- split-bf16 MFMA GEMM (~fp32 precision), fp32 out ----------------
// Y[b][m][n] = sum_k (Ah+Al)[m][k] * (Bh+Bl)[b][n][k], via hh + hl + lh products.
__global__ __launch_bounds__(256) void gemm_mfma_split(
    const unsigned short* __restrict__ Ah, const unsigned short* __restrict__ Al,
    const unsigned short* __restrict__ Bh, const unsigned short* __restrict__ Bl,
    float* __restrict__ Y)
{
    const int n0 = blockIdx.x * 128;
    const int m0 = blockIdx.y * 128;
    const int b  = blockIdx.z;

    __shared__ unsigned short sAh[128 * 32];
    __shared__ unsigned short sAl[128 * 32];
    __shared__ unsigned short sBh[128 * 32];
    __shared__ unsigned short sBl[128 * 32];

    const int t = threadIdx.x;
    const int w = t >> 6;
    const int l = t & 63;

    const size_t aoff = ((size_t)(m0 + w * 32 + (l >> 2))) * DIM + (l & 3) * 8;
    const size_t boff = ((size_t)b * HW + n0 + w * 32 + (l >> 2)) * DIM + (l & 3) * 8;
    const unsigned short* gAh = Ah + aoff;
    const unsigned short* gAl = Al + aoff;
    const unsigned short* gBh = Bh + boff;
    const unsigned short* gBl = Bl + boff;
    const int lbase = (w * 32) * 32;

    f32x4 acc[4][4];
    #pragma unroll
    for (int i = 0; i < 4; ++i)
        #pragma unroll
        for (int j = 0; j < 4; ++j)
            acc[i][j] = (f32x4){0.f, 0.f, 0.f, 0.f};

    const int wm = (w >> 1) * 64, wn = (w & 1) * 64;
    const int fr = l & 15, fk = (l >> 4) * 8;

    for (int k0 = 0; k0 < DIM; k0 += 32) {
        __syncthreads();
        GLOBAL_TO_LDS16(gAh + k0,            &sAh[lbase]);
        GLOBAL_TO_LDS16(gAh + k0 + 16 * DIM, &sAh[lbase + 16 * 32]);
        GLOBAL_TO_LDS16(gAl + k0,            &sAl[lbase]);
        GLOBAL_TO_LDS16(gAl + k0 + 16 * DIM, &sAl[lbase + 16 * 32]);
        GLOBAL_TO_LDS16(gBh + k0,            &sBh[lbase]);
        GLOBAL_TO_LDS16(gBh + k0 + 16 * DIM, &sBh[lbase + 16 * 32]);
        GLOBAL_TO_LDS16(gBl + k0,            &sBl[lbase]);
        GLOBAL_TO_LDS16(gBl + k0 + 16 * DIM, &sBl[lbase + 16 * 32]);
        __syncthreads();

        bf16x8 ah[4], al[4], bh[4], bl[4];
        #pragma unroll
        for (int mi = 0; mi < 4; ++mi) {
            ah[mi] = *(const bf16x8*)&sAh[(wm + mi * 16 + fr) * 32 + fk];
            al[mi] = *(const bf16x8*)&sAl[(wm + mi * 16 + fr) * 32 + fk];
        }
        #pragma unroll
        for (int ni = 0; ni < 4; ++ni) {
            bh[ni] = *(const bf16x8*)&sBh[(wn + ni * 16 + fr) * 32 + fk];
            bl[ni] = *(const bf16x8*)&sBl[(wn + ni * 16 + fr) * 32 + fk];
        }
        #pragma unroll
        for (int mi = 0; mi < 4; ++mi)
            #pragma unroll
            for (int ni = 0; ni < 4; ++ni) {
                acc[mi][ni] = __builtin_amdgcn_mfma_f32_16x16x32_bf16(
                    ah[mi], bh[ni], acc[mi][ni], 0, 0, 0);
                acc[mi][ni] = __builtin_amdgcn_mfma_f32_16x16x32_bf16(
                    ah[mi], bl[ni], acc[mi][ni], 0, 0, 0);
                acc[mi][ni] = __builtin_amdgcn_mfma_f32_16x16x32_bf16(
                    al[mi], bh[ni], acc[mi][ni], 0, 0, 0);
            }
    }

    const int er = (l >> 4) * 4;   // C/D: col=l&15, row=(l>>4)*4+r
    float* Yp = Y + (size_t)b * DIM * HW;
    #pragma unroll
    for (int mi = 0; mi < 4; ++mi)
        #pragma unroll
        for (int ni = 0; ni < 4; ++ni)
            #pragma unroll
            for (int r = 0; r < 4; ++r)
                Yp[(size_t)(m0 + wm + mi * 16 + er + r) * HW + n0 + wn + ni * 16 + fr]
                    = acc[mi][ni][r];
}

// ------------- depthwise 3x3 SAME, fp32 io, optional sumsq -------------
__global__ __launch_bounds__(256) void dwconv_f32(
    const float* __restrict__ in, const float* __restrict__ w9,
    float* __restrict__ out, float* __restrict__ ss, int ss_off)
{
    const int p  = blockIdx.x;             // b*384 + cl
    const int cl = p % DIM;
    const int b  = p / DIM;
    const float* ip = in + (size_t)p * HW;
    float* op = out + (size_t)p * HW;
    float w[9];
    #pragma unroll
    for (int i = 0; i < 9; ++i) w[i] = w9[cl * 9 + i];

    float ssum = 0.f;
    for (int idx = threadIdx.x; idx < HW; idx += 256) {
        const int y = idx >> 7, x = idx & 127;
        float a = 0.f;
        #pragma unroll
        for (int ky = 0; ky < 3; ++ky) {
            const int yy = y + ky - 1;
            if ((unsigned)yy < 128u) {
                #pragma unroll
                for (int kx = 0; kx < 3; ++kx) {
                    const int xx = x + kx - 1;
                    if ((unsigned)xx < 128u)
                        a = fmaf(ip[yy * 128 + xx], w[ky * 3 + kx], a);
                }
            }
        }
        op[idx] = a;
        ssum = fmaf(a, a, ssum);
    }

    if (ss != nullptr) {
        __shared__ float red[256];
        red[threadIdx.x] = ssum;
        __syncthreads();
        for (int s = 128; s > 0; s >>= 1) {
            if (threadIdx.x < s) red[threadIdx.x] += red[threadIdx.x + s];
            __syncthreads();
        }
        if (threadIdx.x == 0) ss[b * (2 * DIM) + ss_off + cl] = red[0];
    }
}

// ------------- raw gram G[b,h,c,d] = sum_n q[c,n]*k[d,n], fp32 in, atomic fp32 partials -------------
#define GCH 512
__global__ __launch_bounds__(256) void gram_qk(
    const float* __restrict__ qA, const float* __restrict__ kA,
    float* __restrict__ G)
{
    const int n0 = blockIdx.x * GCH;
    const int h  = blockIdx.y;
    const int b  = blockIdx.z;
    const float* qb = qA + ((size_t)b * DIM + h * CPH) * HW;
    const float* kb = kA + ((size_t)b * DIM + h * CPH) * HW;

    __shared__ float qs[CPH][132];
    __shared__ float ks[CPH][132];

    const int t  = threadIdx.x;
    const int tx = t & 15, ty = t >> 4;
    float acc[3][3] = {{0.f,0.f,0.f},{0.f,0.f,0.f},{0.f,0.f,0.f}};

    for (int sc = 0; sc < GCH; sc += 128) {
        __syncthreads();
        #pragma unroll
        for (int i = 0; i < 6; ++i) {
            const int idx = t + i * 256;
            const int row = idx >> 5, col = (idx & 31) << 2;
            const size_t g = (size_t)row * HW + n0 + sc + col;
            *(float4*)&qs[row][col] = *(const float4*)&qb[g];
            *(float4*)&ks[row][col] = *(const float4*)&kb[g];
        }
        __syncthreads();
        for (int j = 0; j < 128; j += 4) {
            float qv[3][4], kv[3][4];
            #pragma unroll
            for (int i = 0; i < 3; ++i) {
                const float4 tq = *(const float4*)&qs[ty * 3 + i][j];
                qv[i][0] = tq.x; qv[i][1] = tq.y; qv[i][2] = tq.z; qv[i][3] = tq.w;
                const float4 tk = *(const float4*)&ks[tx * 3 + i][j];
                kv[i][0] = tk.x; kv[i][1] = tk.y; kv[i][2] = tk.z; kv[i][3] = tk.w;
            }
            #pragma unroll
            for (int i = 0; i < 3; ++i)
                #pragma unroll
                for (int jj = 0; jj < 3; ++jj)
                    acc[i][jj] += qv[i][0]*kv[jj][0] + qv[i][1]*kv[jj][1]
                                + qv[i][2]*kv[jj][2] + qv[i][3]*kv[jj][3];
        }
    }

    float* Gp = G + ((size_t)(b * NHEADS + h)) * CPH * CPH;
    #pragma unroll
    for (int i = 0; i < 3; ++i)
        #pragma unroll
        for (int j = 0; j < 3; ++j)
            atomicAdd(&Gp[(ty * 3 + i) * CPH + tx * 3 + j], acc[i][j]);
}

// ------------- normalize + 4x top-k softmax, combined into one P -------------
__global__ void topk_combine(
    const float* __restrict__ G, const float* __restrict__ ss,
    const float* __restrict__ temp,
    const float* __restrict__ a1, const float* __restrict__ a2,
    const float* __restrict__ a3, const float* __restrict__ a4,
    float* __restrict__ P)
{
    const int bh = blockIdx.x;
    const int b = bh >> 3, h = bh & 7;
    const int r = threadIdx.x;
    if (r >= CPH) return;
    const float tpr = temp[h];
    const float* ssb = ss + b * (2 * DIM);
    const float invq = 1.f / sqrtf(ssb[h * CPH + r]);
    const float* Grow = G + ((size_t)bh * CPH + r) * CPH;

    float att[CPH];
    for (int d = 0; d < CPH; ++d)
        att[d] = Grow[d] * invq * (1.f / sqrtf(ssb[DIM + h * CPH + d])) * tpr;

    float s[CPH];
    for (int i = 0; i < CPH; ++i) s[i] = att[i];
    for (int i = 1; i < CPH; ++i) {
        const float key = s[i];
        int j = i - 1;
        while (j >= 0 && s[j] < key) { s[j + 1] = s[j]; --j; }
        s[j + 1] = key;
    }
    // k = 24, 32, 36, 38
    const float thr0 = s[23], thr1 = s[31], thr2 = s[35], thr3 = s[37];
    const float mx = s[0];

    float e[CPH];
    float Z0 = 0.f, Z1 = 0.f, Z2 = 0.f, Z3 = 0.f;
    for (int d = 0; d < CPH; ++d) {
        const float ev = expf(att[d] - mx);
        e[d] = ev;
        if (att[d] >= thr0) Z0 += ev;
        if (att[d] >= thr1) Z1 += ev;
        if (att[d] >= thr2) Z2 += ev;
        if (att[d] >= thr3) Z3 += ev;
    }
    const float w0 = a1[0] / Z0, w1 = a2[0] / Z1, w2 = a3[0] / Z2, w3 = a4[0] / Z3;
    float* Prow = P + ((size_t)bh * CPH + r) * CPH;
    for (int d = 0; d < CPH; ++d) {
        float pv = 0.f;
        if (att[d] >= thr0) pv += w0 * e[d];
        if (att[d] >= thr1) pv += w1 * e[d];
        if (att[d] >= thr2) pv += w2 * e[d];
        if (att[d] >= thr3) pv += w3 * e[d];
        Prow[d] = pv;
    }
}

// ------------- out1t[b][n][hc] = sum_d P * v, fp32 v in, hi/lo bf16 out (transposed) -------------
__global__ __launch_bounds__(256) void pv_apply_split(
    const float* __restrict__ v, const float* __restrict__ P,
    unsigned short* __restrict__ o1h, unsigned short* __restrict__ o1l)
{
    const int bh = blockIdx.y;
    const int b = bh >> 3, h = bh & 7;
    const int n0 = blockIdx.x * 256;

    __shared__ float sPT[CPH][52];            // [d][c]
    __shared__ unsigned short sOh[256 * 48];  // [n_local][c]
    __shared__ unsigned short sOl[256 * 48];
    const int t = threadIdx.x;
    for (int i = t; i < CPH * CPH; i += 256) {
        const int c = i / CPH, d = i % CPH;
        sPT[d][c] = P[(size_t)bh * CPH * CPH + i];
    }
    __syncthreads();

    const int cg = t >> 6;
    const int lane = t & 63;
    const float* vb = v + ((size_t)b * DIM + h * CPH) * HW + n0 + lane * 4;

    float acc[12][4];
    #pragma unroll
    for (int i = 0; i < 12; ++i)
        #pragma unroll
        for (int j = 0; j < 4; ++j) acc[i][j] = 0.f;

    for (int d = 0; d < CPH; ++d) {
        const float4 vv = *(const float4*)&vb[(size_t)d * HW];
        const float vvs[4] = {vv.x, vv.y, vv.z, vv.w};
        #pragma unroll
        for (int cq = 0; cq < 3; ++cq) {
            const float4 pc = *(const float4*)&sPT[d][cg * 12 + cq * 4];
            const float pcs[4] = {pc.x, pc.y, pc.z, pc.w};
            #pragma unroll
            for (int a = 0; a < 4; ++a)
                #pragma unroll
                for (int jn = 0; jn < 4; ++jn)
                    acc[cq * 4 + a][jn] = fmaf(pcs[a], vvs[jn], acc[cq * 4 + a][jn]);
        }
    }

    #pragma unroll
    for (int jn = 0; jn < 4; ++jn)
        #pragma unroll
        for (int cq = 0; cq < 3; ++cq)
            #pragma unroll
            for (int a = 0; a < 4; ++a) {
                const float val = acc[cq * 4 + a][jn];
                const unsigned short hh = f2b(val);
                sOh[(lane * 4 + jn) * 48 + cg * 12 + cq * 4 + a] = hh;
                sOl[(lane * 4 + jn) * 48 + cg * 12 + cq * 4 + a] = f2b(val - b2f(hh));
            }
    __syncthreads();

    unsigned short* dh = o1h + ((size_t)b * HW + n0 + t) * DIM + h * CPH;
    unsigned short* dl = o1l + ((size_t)b * HW + n0 + t) * DIM + h * CPH;
    #pragma unroll
    for (int i = 0; i < 6; ++i) {
        *(uint4*)&dh[i * 8] = *(const uint4*)&sOh[t * 48 + i * 8];
        *(uint4*)&dl[i * 8] = *(const uint4*)&sOl[t * 48 + i * 8];
    }
}

extern "C" void kernel_launch(void* const* d_in, const int* in_sizes, int n_in,
                              void* d_out, int out_size, void* d_ws, size_t ws_size,
                              hipStream_t stream)
{
    const float* x      = (const float*)d_in[0];
    const float* qkv_w  = (const float*)d_in[1];
    const float* dw_w   = (const float*)d_in[2];
    const float* proj_w = (const float*)d_in[3];
    const float* temp   = (const float*)d_in[4];
    const float* a1 = (const float*)d_in[5];
    const float* a2 = (const float*)d_in[6];
    const float* a3 = (const float*)d_in[7];
    const float* a4 = (const float*)d_in[8];
    float* out = (float*)d_out;

    const size_t PBE = (size_t)HW * DIM;        // per-batch elems (6,291,456)
    const size_t WQE = (size_t)1152 * 384;
    const size_t WPE = (size_t)384 * 384;

    // bytes needed when processing nb batches per pass:
    // A,B (bf16 xt hi/lo -> out1 hi/lo) + C,D,E (fp32 raw / q~|v~ / k~) + weights + small
    auto need_for = [&](size_t nb) -> size_t {
        return nb * PBE * 2 * 2 + nb * PBE * 4 * 3
             + (2 * WQE + 2 * WPE) * 2
             + (nb * 768 + 2 * nb * NHEADS * CPH * CPH) * 4;
    };

    int nb, npass;
    if      (ws_size >= need_for(4)) { nb = 4; npass = 1; }
    else if (ws_size >= need_for(1)) { nb = 1; npass = 4; }
    else return;   // readable failure instead of OOB crash

    unsigned short* A  = (unsigned short*)d_ws;     // xt_hi -> out1t_hi [nb][HW][384]
    unsigned short* Bq = A + (size_t)nb * PBE;      // xt_lo -> out1t_lo
    float* C = (float*)(Bq + (size_t)nb * PBE);     // raw q/k/v fp32 [nb][384][HW]
    float* D = C + (size_t)nb * PBE;                // q~ fp32 -> v~ fp32
    float* E = D + (size_t)nb * PBE;                // k~ fp32
    unsigned short* wqh = (unsigned short*)(E + (size_t)nb * PBE);
    unsigned short* wql = wqh + WQE;
    unsigned short* wph = wql + WQE;
    unsigned short* wpl = wph + WPE;
    float* buf_ss = (float*)(wpl + WPE);                      // [nb][768]
    float* buf_G  = buf_ss + (size_t)nb * 768;                // [nb][8][48][48]
    float* buf_P  = buf_G + (size_t)nb * NHEADS * CPH * CPH;

    cvt_w<<<dim3((1152 * 384 + 255) / 256), 256, 0, stream>>>(qkv_w, wqh, wql, 1152 * 384);
    cvt_w<<<dim3((384 * 384 + 255) / 256), 256, 0, stream>>>(proj_w, wph, wpl, 384 * 384);

    for (int p = 0; p < npass; ++p) {
        const int b0 = p * nb;
        const float* xp   = x   + (size_t)b0 * PBE;
        float*       outp = out + (size_t)b0 * PBE;

        const dim3 ggrid(HW / 128, DIM / 128, nb);
        const dim3 dgrid(nb * DIM);

        transpose_cvt<<<dim3(HW / 256, DIM / 16, nb), 256, 0, stream>>>(xp, A, Bq);

        // q path: split GEMM -> C (fp32), dwconv+ss -> D
        gemm_mfma_split<<<ggrid, 256, 0, stream>>>(wqh, wql, A, Bq, C);
        dwconv_f32<<<dgrid, 256, 0, stream>>>(C, dw_w, D, buf_ss, 0);
        // k path: split GEMM -> C, dwconv+ss -> E
        gemm_mfma_split<<<ggrid, 256, 0, stream>>>(wqh + (size_t)DIM * DIM,
                                                   wql + (size_t)DIM * DIM, A, Bq, C);
        dwconv_f32<<<dgrid, 256, 0, stream>>>(C, dw_w + (size_t)DIM * 9, E, buf_ss, DIM);

        hipMemsetAsync(buf_G, 0, (size_t)nb * NHEADS * CPH * CPH * sizeof(float), stream);
        gram_qk<<<dim3(HW / GCH, NHEADS, nb), 256, 0, stream>>>(D, E, buf_G);
        topk_combine<<<dim3(nb * NHEADS), 64, 0, stream>>>(
            buf_G, buf_ss, temp, a1, a2, a3, a4, buf_P);

        // v path: split GEMM -> C, dwconv -> D (q~ dead after gram)
        gemm_mfma_split<<<ggrid, 256, 0, stream>>>(wqh + (size_t)2 * DIM * DIM,
                                                   wql + (size_t)2 * DIM * DIM, A, Bq, C);
        dwconv_f32<<<dgrid, 256, 0, stream>>>(C, dw_w + (size_t)2 * DIM * 9, D, nullptr, 0);

        // out1^T hi/lo -> A,B (xt dead after v GEMM)
        pv_apply_split<<<dim3(HW / 256, nb * NHEADS), 256, 0, stream>>>(D, buf_P, A, Bq);

        // proj: split GEMM -> out (fp32)
        gemm_mfma_split<<<ggrid, 256, 0, stream>>>(wph, wpl, A, Bq, outp);
    }
}

// Round 6
// 1334.854 us; speedup vs baseline: 1.8172x; 1.8172x over previous
//
#include <hip/hip_runtime.h>

#define NHEADS 8
#define DIM 384
#define BB 4
#define HW 16384      // 128*128
#define CPH 48        // channels per head

typedef unsigned int u32;
typedef __attribute__((ext_vector_type(8))) short bf16x8;
typedef __attribute__((ext_vector_type(4))) float f32x4;

__device__ __forceinline__ float b2f(unsigned short u) {
    union { u32 i; float f; } x; x.i = ((u32)u) << 16; return x.f;
}
__device__ __forceinline__ unsigned short f2b(float f) {
    u32 x = __float_as_uint(f);
    u32 r = (x + 0x7fffu + ((x >> 16) & 1u)) >> 16;   // RNE
    return (unsigned short)r;
}

__device__ __forceinline__ float wave_min(float v) {
    #pragma unroll
    for (int off = 32; off; off >>= 1) v = fminf(v, __shfl_xor(v, off));
    return v;
}
__device__ __forceinline__ float wave_max(float v) {
    #pragma unroll
    for (int off = 32; off; off >>= 1) v = fmaxf(v, __shfl_xor(v, off));
    return v;
}
__device__ __forceinline__ float wave_sum(float v) {
    #pragma unroll
    for (int off = 32; off; off >>= 1) v += __shfl_xor(v, off);
    return v;
}

// async global->LDS, 16B per lane; LDS dest = wave-uniform base + lane*16
#define GLOBAL_TO_LDS16(gsrc, ldst)                                           \
    __builtin_amdgcn_global_load_lds(                                         \
        (const __attribute__((address_space(1))) u32*)(gsrc),                 \
        (__attribute__((address_space(3))) u32*)(ldst), 16, 0, 0)

// ---------------- fp32 -> bf16 hi/lo split (weights) ----------------
__global__ void cvt_w(const float* __restrict__ a,
                      unsigned short* __restrict__ hi, unsigned short* __restrict__ lo, int n)
{
    const int i = blockIdx.x * 256 + threadIdx.x;
    if (i < n) {
        const float v = a[i];
        const unsigned short h = f2b(v);
        hi[i] = h;
        lo[i] = f2b(v - b2f(h));
    }
}

// ---------------- x[b][c][n] fp32 -> xt_hi/xt_lo[b][n][c] bf16 ----------------
__global__ __launch_bounds__(256) void transpose_cvt(
    const float* __restrict__ x,
    unsigned short* __restrict__ xth, unsigned short* __restrict__ xtl)
{
    const int n  = blockIdx.x * 256 + threadIdx.x;
    const int c0 = blockIdx.y * 16;
    const int b  = blockIdx.z;
    const float* xp = x + ((size_t)b * DIM + c0) * HW + n;
    alignas(16) unsigned short th[16];
    alignas(16) unsigned short tl[16];
    #pragma unroll
    for (int j = 0; j < 16; ++j) {
        const float v = xp[(size_t)j * HW];
        const unsigned short h = f2b(v);
        th[j] = h;
        tl[j] = f2b(v - b2f(h));
    }
    unsigned short* oh = xth + ((size_t)b * HW + n) * DIM + c0;
    unsigned short* ol = xtl + ((size_t)b * HW + n) * DIM + c0;
    *(uint4*)&oh[0] = *(const uint4*)&th[0];
    *(uint4*)&oh[8] = *(const uint4*)&th[8];
    *(uint4*)&ol[0] = *(const uint4*)&tl[0];
    *(uint4*)&ol[8] = *(const uint4*)&tl[8];
}

// ---------------- split-bf16 MFMA GEMM (~fp32 precision), fp32 out ----------------
__global__ __launch_bounds__(256) void gemm_mfma_split(
    const unsigned short* __restrict__ Ah, const unsigned short* __restrict__ Al,
    const unsigned short* __restrict__ Bh, const unsigned short* __restrict__ Bl,
    float* __restrict__ Y)
{
    const int n0 = blockIdx.x * 128;
    const int m0 = blockIdx.y * 128;
    const int b  = blockIdx.z;

    __shared__ unsigned short sAh[128 * 32];
    __shared__ unsigned short sAl[128 * 32];
    __shared__ unsigned short sBh[128 * 32];
    __shared__ unsigned short sBl[128 * 32];

    const int t = threadIdx.x;
    const int w = t >> 6;
    const int l = t & 63;

    const size_t aoff = ((size_t)(m0 + w * 32 + (l >> 2))) * DIM + (l & 3) * 8;
    const size_t boff = ((size_t)b * HW + n0 + w * 32 + (l >> 2)) * DIM + (l & 3) * 8;
    const unsigned short* gAh = Ah + aoff;
    const unsigned short* gAl = Al + aoff;
    const unsigned short* gBh = Bh + boff;
    const unsigned short* gBl = Bl + boff;
    const int lbase = (w * 32) * 32;

    f32x4 acc[4][4];
    #pragma unroll
    for (int i = 0; i < 4; ++i)
        #pragma unroll
        for (int j = 0; j < 4; ++j)
            acc[i][j] = (f32x4){0.f, 0.f, 0.f, 0.f};

    const int wm = (w >> 1) * 64, wn = (w & 1) * 64;
    const int fr = l & 15, fk = (l >> 4) * 8;

    for (int k0 = 0; k0 < DIM; k0 += 32) {
        __syncthreads();
        GLOBAL_TO_LDS16(gAh + k0,            &sAh[lbase]);
        GLOBAL_TO_LDS16(gAh + k0 + 16 * DIM, &sAh[lbase + 16 * 32]);
        GLOBAL_TO_LDS16(gAl + k0,            &sAl[lbase]);
        GLOBAL_TO_LDS16(gAl + k0 + 16 * DIM, &sAl[lbase + 16 * 32]);
        GLOBAL_TO_LDS16(gBh + k0,            &sBh[lbase]);
        GLOBAL_TO_LDS16(gBh + k0 + 16 * DIM, &sBh[lbase + 16 * 32]);
        GLOBAL_TO_LDS16(gBl + k0,            &sBl[lbase]);
        GLOBAL_TO_LDS16(gBl + k0 + 16 * DIM, &sBl[lbase + 16 * 32]);
        __syncthreads();

        bf16x8 ah[4], al[4], bh[4], bl[4];
        #pragma unroll
        for (int mi = 0; mi < 4; ++mi) {
            ah[mi] = *(const bf16x8*)&sAh[(wm + mi * 16 + fr) * 32 + fk];
            al[mi] = *(const bf16x8*)&sAl[(wm + mi * 16 + fr) * 32 + fk];
        }
        #pragma unroll
        for (int ni = 0; ni < 4; ++ni) {
            bh[ni] = *(const bf16x8*)&sBh[(wn + ni * 16 + fr) * 32 + fk];
            bl[ni] = *(const bf16x8*)&sBl[(wn + ni * 16 + fr) * 32 + fk];
        }
        #pragma unroll
        for (int mi = 0; mi < 4; ++mi)
            #pragma unroll
            for (int ni = 0; ni < 4; ++ni) {
                acc[mi][ni] = __builtin_amdgcn_mfma_f32_16x16x32_bf16(
                    ah[mi], bh[ni], acc[mi][ni], 0, 0, 0);
                acc[mi][ni] = __builtin_amdgcn_mfma_f32_16x16x32_bf16(
                    ah[mi], bl[ni], acc[mi][ni], 0, 0, 0);
                acc[mi][ni] = __builtin_amdgcn_mfma_f32_16x16x32_bf16(
                    al[mi], bh[ni], acc[mi][ni], 0, 0, 0);
            }
    }

    const int er = (l >> 4) * 4;   // C/D: col=l&15, row=(l>>4)*4+r
    float* Yp = Y + (size_t)b * DIM * HW;
    #pragma unroll
    for (int mi = 0; mi < 4; ++mi)
        #pragma unroll
        for (int ni = 0; ni < 4; ++ni)
            #pragma unroll
            for (int r = 0; r < 4; ++r)
                Yp[(size_t)(m0 + wm + mi * 16 + er + r) * HW + n0 + wn + ni * 16 + fr]
                    = acc[mi][ni][r];
}

// ------------- depthwise 3x3 SAME, fp32 io, optional sumsq -------------
__global__ __launch_bounds__(256) void dwconv_f32(
    const float* __restrict__ in, const float* __restrict__ w9,
    float* __restrict__ out, float* __restrict__ ss, int ss_off)
{
    const int p  = blockIdx.x;             // b*384 + cl
    const int cl = p % DIM;
    const int b  = p / DIM;
    const float* ip = in + (size_t)p * HW;
    float* op = out + (size_t)p * HW;
    float w[9];
    #pragma unroll
    for (int i = 0; i < 9; ++i) w[i] = w9[cl * 9 + i];

    float ssum = 0.f;
    for (int idx = threadIdx.x; idx < HW; idx += 256) {
        const int y = idx >> 7, x = idx & 127;
        float a = 0.f;
        #pragma unroll
        for (int ky = 0; ky < 3; ++ky) {
            const int yy = y + ky - 1;
            if ((unsigned)yy < 128u) {
                #pragma unroll
                for (int kx = 0; kx < 3; ++kx) {
                    const int xx = x + kx - 1;
                    if ((unsigned)xx < 128u)
                        a = fmaf(ip[yy * 128 + xx], w[ky * 3 + kx], a);
                }
            }
        }
        op[idx] = a;
        ssum = fmaf(a, a, ssum);
    }

    if (ss != nullptr) {
        __shared__ float red[256];
        red[threadIdx.x] = ssum;
        __syncthreads();
        for (int s = 128; s > 0; s >>= 1) {
            if (threadIdx.x < s) red[threadIdx.x] += red[threadIdx.x + s];
            __syncthreads();
        }
        if (threadIdx.x == 0) ss[b * (2 * DIM) + ss_off + cl] = red[0];
    }
}

// ------------- raw gram G[b,h,c,d] = sum_n q[c,n]*k[d,n], fp32 in, atomic fp32 partials -------------
#define GCH 512
__global__ __launch_bounds__(256) void gram_qk(
    const float* __restrict__ qA, const float* __restrict__ kA,
    float* __restrict__ G)
{
    const int n0 = blockIdx.x * GCH;
    const int h  = blockIdx.y;
    const int b  = blockIdx.z;
    const float* qb = qA + ((size_t)b * DIM + h * CPH) * HW;
    const float* kb = kA + ((size_t)b * DIM + h * CPH) * HW;

    __shared__ float qs[CPH][132];
    __shared__ float ks[CPH][132];

    const int t  = threadIdx.x;
    const int tx = t & 15, ty = t >> 4;
    float acc[3][3] = {{0.f,0.f,0.f},{0.f,0.f,0.f},{0.f,0.f,0.f}};

    for (int sc = 0; sc < GCH; sc += 128) {
        __syncthreads();
        #pragma unroll
        for (int i = 0; i < 6; ++i) {
            const int idx = t + i * 256;
            const int row = idx >> 5, col = (idx & 31) << 2;
            const size_t g = (size_t)row * HW + n0 + sc + col;
            *(float4*)&qs[row][col] = *(const float4*)&qb[g];
            *(float4*)&ks[row][col] = *(const float4*)&kb[g];
        }
        __syncthreads();
        for (int j = 0; j < 128; j += 4) {
            float qv[3][4], kv[3][4];
            #pragma unroll
            for (int i = 0; i < 3; ++i) {
                const float4 tq = *(const float4*)&qs[ty * 3 + i][j];
                qv[i][0] = tq.x; qv[i][1] = tq.y; qv[i][2] = tq.z; qv[i][3] = tq.w;
                const float4 tk = *(const float4*)&ks[tx * 3 + i][j];
                kv[i][0] = tk.x; kv[i][1] = tk.y; kv[i][2] = tk.z; kv[i][3] = tk.w;
            }
            #pragma unroll
            for (int i = 0; i < 3; ++i)
                #pragma unroll
                for (int jj = 0; jj < 3; ++jj)
                    acc[i][jj] += qv[i][0]*kv[jj][0] + qv[i][1]*kv[jj][1]
                                + qv[i][2]*kv[jj][2] + qv[i][3]*kv[jj][3];
        }
    }

    float* Gp = G + ((size_t)(b * NHEADS + h)) * CPH * CPH;
    #pragma unroll
    for (int i = 0; i < 3; ++i)
        #pragma unroll
        for (int j = 0; j < 3; ++j)
            atomicAdd(&Gp[(ty * 3 + i) * CPH + tx * 3 + j], acc[i][j]);
}

// ------------- normalize + 4x top-k softmax combined into one P (one wave per row) -------------
// grid: nb*NHEADS*CPH blocks of 64. Lane d holds att[d]; rank via 48 shuffles;
// k-th largest = min{att : cnt_gt < k} (tie semantics == lax.top_k + >=).
__global__ __launch_bounds__(64) void topk_combine(
    const float* __restrict__ G, const float* __restrict__ ss,
    const float* __restrict__ temp,
    const float* __restrict__ a1, const float* __restrict__ a2,
    const float* __restrict__ a3, const float* __restrict__ a4,
    float* __restrict__ P)
{
    const int row = blockIdx.x;           // bh*48 + r
    const int bh  = row / CPH;
    const int r   = row - bh * CPH;
    const int b = bh >> 3, h = bh & 7;
    const int l = threadIdx.x;

    const float tpr = temp[h];
    const float* ssb = ss + b * (2 * DIM);
    const float invq = 1.f / sqrtf(ssb[h * CPH + r]);

    float att = -3.0e38f;
    if (l < CPH)
        att = G[(size_t)row * CPH + l] * invq * (1.f / sqrtf(ssb[DIM + h * CPH + l])) * tpr;

    int cnt = 0;                          // # strictly greater
    #pragma unroll
    for (int i = 0; i < CPH; ++i)
        cnt += (__shfl(att, i) > att) ? 1 : 0;

    const float mx   = wave_max(att);
    const float thr0 = wave_min((l < CPH && cnt < 24) ? att : 3.0e38f);
    const float thr1 = wave_min((l < CPH && cnt < 32) ? att : 3.0e38f);
    const float thr2 = wave_min((l < CPH && cnt < 36) ? att : 3.0e38f);
    const float thr3 = wave_min((l < CPH && cnt < 38) ? att : 3.0e38f);

    const float e = (l < CPH) ? expf(att - mx) : 0.f;
    const float Z0 = wave_sum(att >= thr0 ? e : 0.f);
    const float Z1 = wave_sum(att >= thr1 ? e : 0.f);
    const float Z2 = wave_sum(att >= thr2 ? e : 0.f);
    const float Z3 = wave_sum(att >= thr3 ? e : 0.f);

    const float w0 = a1[0] / Z0, w1 = a2[0] / Z1, w2 = a3[0] / Z2, w3 = a4[0] / Z3;
    float pv = 0.f;
    if (att >= thr0) pv += w0 * e;
    if (att >= thr1) pv += w1 * e;
    if (att >= thr2) pv += w2 * e;
    if (att >= thr3) pv += w3 * e;
    if (l < CPH) P[(size_t)row * CPH + l] = pv;
}

// ------------- out1t[b][n][hc] = sum_d P * v, fp32 v in, hi/lo bf16 out (transposed) -------------
__global__ __launch_bounds__(256) void pv_apply_split(
    const float* __restrict__ v, const float* __restrict__ P,
    unsigned short* __restrict__ o1h, unsigned short* __restrict__ o1l)
{
    const int bh = blockIdx.y;
    const int b = bh >> 3, h = bh & 7;
    const int n0 = blockIdx.x * 256;

    __shared__ float sPT[CPH][52];            // [d][c]
    __shared__ unsigned short sOh[256 * 48];  // [n_local][c]
    __shared__ unsigned short sOl[256 * 48];
    const int t = threadIdx.x;
    for (int i = t; i < CPH * CPH; i += 256) {
        const int c = i / CPH, d = i % CPH;
        sPT[d][c] = P[(size_t)bh * CPH * CPH + i];
    }
    __syncthreads();

    const int cg = t >> 6;
    const int lane = t & 63;
    const float* vb = v + ((size_t)b * DIM + h * CPH) * HW + n0 + lane * 4;

    float acc[12][4];
    #pragma unroll
    for (int i = 0; i < 12; ++i)
        #pragma unroll
        for (int j = 0; j < 4; ++j) acc[i][j] = 0.f;

    for (int d = 0; d < CPH; ++d) {
        const float4 vv = *(const float4*)&vb[(size_t)d * HW];
        const float vvs[4] = {vv.x, vv.y, vv.z, vv.w};
        #pragma unroll
        for (int cq = 0; cq < 3; ++cq) {
            const float4 pc = *(const float4*)&sPT[d][cg * 12 + cq * 4];
            const float pcs[4] = {pc.x, pc.y, pc.z, pc.w};
            #pragma unroll
            for (int a = 0; a < 4; ++a)
                #pragma unroll
                for (int jn = 0; jn < 4; ++jn)
                    acc[cq * 4 + a][jn] = fmaf(pcs[a], vvs[jn], acc[cq * 4 + a][jn]);
        }
    }

    #pragma unroll
    for (int jn = 0; jn < 4; ++jn)
        #pragma unroll
        for (int cq = 0; cq < 3; ++cq)
            #pragma unroll
            for (int a = 0; a < 4; ++a) {
                const float val = acc[cq * 4 + a][jn];
                const unsigned short hh = f2b(val);
                sOh[(lane * 4 + jn) * 48 + cg * 12 + cq * 4 + a] = hh;
                sOl[(lane * 4 + jn) * 48 + cg * 12 + cq * 4 + a] = f2b(val - b2f(hh));
            }
    __syncthreads();

    unsigned short* dh = o1h + ((size_t)b * HW + n0 + t) * DIM + h * CPH;
    unsigned short* dl = o1l + ((size_t)b * HW + n0 + t) * DIM + h * CPH;
    #pragma unroll
    for (int i = 0; i < 6; ++i) {
        *(uint4*)&dh[i * 8] = *(const uint4*)&sOh[t * 48 + i * 8];
        *(uint4*)&dl[i * 8] = *(const uint4*)&sOl[t * 48 + i * 8];
    }
}

extern "C" void kernel_launch(void* const* d_in, const int* in_sizes, int n_in,
                              void* d_out, int out_size, void* d_ws, size_t ws_size,
                              hipStream_t stream)
{
    const float* x      = (const float*)d_in[0];
    const float* qkv_w  = (const float*)d_in[1];
    const float* dw_w   = (const float*)d_in[2];
    const float* proj_w = (const float*)d_in[3];
    const float* temp   = (const float*)d_in[4];
    const float* a1 = (const float*)d_in[5];
    const float* a2 = (const float*)d_in[6];
    const float* a3 = (const float*)d_in[7];
    const float* a4 = (const float*)d_in[8];
    float* out = (float*)d_out;

    const size_t PBE = (size_t)HW * DIM;        // per-batch elems (6,291,456)
    const size_t WQE = (size_t)1152 * 384;
    const size_t WPE = (size_t)384 * 384;

    auto need_for = [&](size_t nb) -> size_t {
        return nb * PBE * 16                       // A,B bf16 + C,D,E fp32
             + (2 * WQE + 2 * WPE) * 2
             + (nb * 768 + 2 * nb * NHEADS * CPH * CPH) * 4;
    };

    int nb, npass;
    if      (ws_size >= need_for(4)) { nb = 4; npass = 1; }
    else if (ws_size >= need_for(2)) { nb = 2; npass = 2; }
    else if (ws_size >= need_for(1)) { nb = 1; npass = 4; }
    else return;

    unsigned short* A  = (unsigned short*)d_ws;     // xt_hi -> out1t_hi [nb][HW][384]
    unsigned short* Bq = A + (size_t)nb * PBE;      // xt_lo -> out1t_lo
    float* C = (float*)(Bq + (size_t)nb * PBE);     // raw q/k/v fp32 [nb][384][HW]
    float* D = C + (size_t)nb * PBE;                // q~ fp32 -> v~ fp32
    float* E = D + (size_t)nb * PBE;                // k~ fp32
    unsigned short* wqh = (unsigned short*)(E + (size_t)nb * PBE);
    unsigned short* wql = wqh + WQE;
    unsigned short* wph = wql + WQE;
    unsigned short* wpl = wph + WPE;
    float* buf_ss = (float*)(wpl + WPE);                      // [nb][768]
    float* buf_G  = buf_ss + (size_t)nb * 768;                // [nb][8][48][48]
    float* buf_P  = buf_G + (size_t)nb * NHEADS * CPH * CPH;

    cvt_w<<<dim3((1152 * 384 + 255) / 256), 256, 0, stream>>>(qkv_w, wqh, wql, 1152 * 384);
    cvt_w<<<dim3((384 * 384 + 255) / 256), 256, 0, stream>>>(proj_w, wph, wpl, 384 * 384);

    for (int p = 0; p < npass; ++p) {
        const int b0 = p * nb;
        const float* xp   = x   + (size_t)b0 * PBE;
        float*       outp = out + (size_t)b0 * PBE;

        const dim3 ggrid(HW / 128, DIM / 128, nb);
        const dim3 dgrid(nb * DIM);

        transpose_cvt<<<dim3(HW / 256, DIM / 16, nb), 256, 0, stream>>>(xp, A, Bq);

        // q path: split GEMM -> C (fp32), dwconv+ss -> D
        gemm_mfma_split<<<ggrid, 256, 0, stream>>>(wqh, wql, A, Bq, C);
        dwconv_f32<<<dgrid, 256, 0, stream>>>(C, dw_w, D, buf_ss, 0);
        // k path: split GEMM -> C, dwconv+ss -> E
        gemm_mfma_split<<<ggrid, 256, 0, stream>>>(wqh + (size_t)DIM * DIM,
                                                   wql + (size_t)DIM * DIM, A, Bq, C);
        dwconv_f32<<<dgrid, 256, 0, stream>>>(C, dw_w + (size_t)DIM * 9, E, buf_ss, DIM);

        hipMemsetAsync(buf_G, 0, (size_t)nb * NHEADS * CPH * CPH * sizeof(float), stream);
        gram_qk<<<dim3(HW / GCH, NHEADS, nb), 256, 0, stream>>>(D, E, buf_G);
        topk_combine<<<dim3(nb * NHEADS * CPH), 64, 0, stream>>>(
            buf_G, buf_ss, temp, a1, a2, a3, a4, buf_P);

        // v path: split GEMM -> C, dwconv -> D (q~ dead after gram)
        gemm_mfma_split<<<ggrid, 256, 0, stream>>>(wqh + (size_t)2 * DIM * DIM,
                                                   wql + (size_t)2 * DIM * DIM, A, Bq, C);
        dwconv_f32<<<dgrid, 256, 0, stream>>>(C, dw_w + (size_t)2 * DIM * 9, D, nullptr, 0);

        // out1^T hi/lo -> A,B (xt dead after v GEMM)
        pv_apply_split<<<dim3(HW / 256, nb * NHEADS), 256, 0, stream>>>(D, buf_P, A, Bq);

        // proj: split GEMM -> out (fp32)
        gemm_mfma_split<<<ggrid, 256, 0, stream>>>(wph, wpl, A, Bq, outp);
    }
}

// Round 7
// 587.525 us; speedup vs baseline: 4.1286x; 2.2720x over previous
//
#include <hip/hip_runtime.h>

#define NHEADS 8
#define DIM 384
#define BB 4
#define HW 16384      // 128*128
#define CPH 48        // channels per head

typedef unsigned int u32;
typedef _Float16 f16x8 __attribute__((ext_vector_type(8)));
typedef _Float16 f16x4 __attribute__((ext_vector_type(4)));
typedef __attribute__((ext_vector_type(4))) float f32x4;

__device__ __forceinline__ float wave_min(float v) {
    #pragma unroll
    for (int off = 32; off; off >>= 1) v = fminf(v, __shfl_xor(v, off));
    return v;
}
__device__ __forceinline__ float wave_max(float v) {
    #pragma unroll
    for (int off = 32; off; off >>= 1) v = fmaxf(v, __shfl_xor(v, off));
    return v;
}
__device__ __forceinline__ float wave_sum(float v) {
    #pragma unroll
    for (int off = 32; off; off >>= 1) v += __shfl_xor(v, off);
    return v;
}

// async global->LDS, 16B per lane; LDS dest = wave-uniform base + lane*16
#define GLOBAL_TO_LDS16(gsrc, ldst)                                           \
    __builtin_amdgcn_global_load_lds(                                         \
        (const __attribute__((address_space(1))) u32*)(gsrc),                 \
        (__attribute__((address_space(3))) u32*)(ldst), 16, 0, 0)

// ---------------- fp32 -> fp16 weight convert ----------------
__global__ void cvt_w(const float* __restrict__ a, _Float16* __restrict__ o, int n)
{
    const int i = blockIdx.x * 256 + threadIdx.x;
    if (i < n) o[i] = (_Float16)a[i];
}

// ---------------- x[b][c][n] fp32 -> xt[b][n][c] fp16 ----------------
__global__ __launch_bounds__(256) void transpose_cvt(
    const float* __restrict__ x, _Float16* __restrict__ xt)
{
    const int n  = blockIdx.x * 256 + threadIdx.x;
    const int c0 = blockIdx.y * 16;
    const int b  = blockIdx.z;
    const float* xp = x + ((size_t)b * DIM + c0) * HW + n;
    alignas(16) _Float16 th[16];
    #pragma unroll
    for (int j = 0; j < 16; ++j) th[j] = (_Float16)xp[(size_t)j * HW];
    _Float16* op = xt + ((size_t)b * HW + n) * DIM + c0;
    *(f16x8*)&op[0] = *(const f16x8*)&th[0];
    *(f16x8*)&op[8] = *(const f16x8*)&th[8];
}

// ---------------- fp16 MFMA GEMM: Y[b][m][n] = sum_k W[m][k]*Xt[b][n][k] ----------------
// Y: fp16 (out_f32=0) or fp32 (out_f32=1).
__global__ __launch_bounds__(256) void gemm_f16(
    const _Float16* __restrict__ W, const _Float16* __restrict__ Xt,
    void* __restrict__ Y, int out_f32)
{
    const int n0 = blockIdx.x * 128;
    const int m0 = blockIdx.y * 128;
    const int b  = blockIdx.z;

    __shared__ _Float16 sA[128 * 32];   // [m][k]
    __shared__ _Float16 sB[128 * 32];   // [n][k]

    const int t = threadIdx.x;
    const int w = t >> 6;
    const int l = t & 63;

    const _Float16* gA = W  + ((size_t)(m0 + w * 32 + (l >> 2))) * DIM + (l & 3) * 8;
    const _Float16* gB = Xt + ((size_t)b * HW + n0 + w * 32 + (l >> 2)) * DIM + (l & 3) * 8;
    _Float16* lA = &sA[(w * 32) * 32];
    _Float16* lB = &sB[(w * 32) * 32];

    f32x4 acc[4][4];
    #pragma unroll
    for (int i = 0; i < 4; ++i)
        #pragma unroll
        for (int j = 0; j < 4; ++j)
            acc[i][j] = (f32x4){0.f, 0.f, 0.f, 0.f};

    const int wm = (w >> 1) * 64, wn = (w & 1) * 64;
    const int fr = l & 15, fk = (l >> 4) * 8;

    for (int k0 = 0; k0 < DIM; k0 += 32) {
        __syncthreads();
        GLOBAL_TO_LDS16(gA + k0,             lA);
        GLOBAL_TO_LDS16(gA + k0 + 16 * DIM,  lA + 16 * 32);
        GLOBAL_TO_LDS16(gB + k0,             lB);
        GLOBAL_TO_LDS16(gB + k0 + 16 * DIM,  lB + 16 * 32);
        __syncthreads();

        f16x8 af[4], bfv[4];
        #pragma unroll
        for (int mi = 0; mi < 4; ++mi)
            af[mi] = *(const f16x8*)&sA[(wm + mi * 16 + fr) * 32 + fk];
        #pragma unroll
        for (int ni = 0; ni < 4; ++ni)
            bfv[ni] = *(const f16x8*)&sB[(wn + ni * 16 + fr) * 32 + fk];
        #pragma unroll
        for (int mi = 0; mi < 4; ++mi)
            #pragma unroll
            for (int ni = 0; ni < 4; ++ni)
                acc[mi][ni] = __builtin_amdgcn_mfma_f32_16x16x32_f16(
                    af[mi], bfv[ni], acc[mi][ni], 0, 0, 0);
    }

    const int er = (l >> 4) * 4;   // C/D: col=l&15, row=(l>>4)*4+r
    if (out_f32) {
        float* Yp = (float*)Y + (size_t)b * DIM * HW;
        #pragma unroll
        for (int mi = 0; mi < 4; ++mi)
            #pragma unroll
            for (int ni = 0; ni < 4; ++ni)
                #pragma unroll
                for (int r = 0; r < 4; ++r)
                    Yp[(size_t)(m0 + wm + mi * 16 + er + r) * HW + n0 + wn + ni * 16 + fr]
                        = acc[mi][ni][r];
    } else {
        _Float16* Yp = (_Float16*)Y + (size_t)b * DIM * HW;
        #pragma unroll
        for (int mi = 0; mi < 4; ++mi)
            #pragma unroll
            for (int ni = 0; ni < 4; ++ni)
                #pragma unroll
                for (int r = 0; r < 4; ++r)
                    Yp[(size_t)(m0 + wm + mi * 16 + er + r) * HW + n0 + wn + ni * 16 + fr]
                        = (_Float16)acc[mi][ni][r];
    }
}

// ------------- depthwise 3x3 SAME, fp16 io, LDS-tiled, optional sumsq -------------
// Block = (plane p, 32-row tile j). LDS tile: 34 rows x 136 halfs, data at col 8,
// zero halo everywhere else (handles x and y borders without guards).
__global__ __launch_bounds__(256) void dwconv_f16(
    const _Float16* __restrict__ in, const float* __restrict__ w9,
    _Float16* __restrict__ out, float* __restrict__ ss, int ss_off)
{
    const int j  = blockIdx.x & 3;
    const int p  = blockIdx.x >> 2;        // b*384 + cl
    const int cl = p % DIM;
    const int b  = p / DIM;
    const int r0 = j * 32;

    __shared__ __align__(16) _Float16 tile[34 * 136 + 8];   // 4632 halfs
    const int t = threadIdx.x;

    const uint4 z4 = make_uint4(0, 0, 0, 0);
    for (int i = t; i < 579; i += 256)
        *(uint4*)&tile[i * 8] = z4;
    __syncthreads();

    const _Float16* ip = in + (size_t)p * HW;
    for (int c = t; c < 34 * 16; c += 256) {
        const int i = c >> 4, seg = c & 15;
        const int g = r0 - 1 + i;
        if ((unsigned)g < 128u)
            *(f16x8*)&tile[i * 136 + 8 + seg * 8] = *(const f16x8*)&ip[g * 128 + seg * 8];
    }

    float w[9];
    #pragma unroll
    for (int i = 0; i < 9; ++i) w[i] = w9[cl * 9 + i];
    __syncthreads();

    const int yr = t >> 3;            // 0..31
    const int xc = (t & 7) * 16;      // 0..112

    float acc[16];
    #pragma unroll
    for (int c = 0; c < 16; ++c) acc[c] = 0.f;

    #pragma unroll
    for (int dy = 0; dy < 3; ++dy) {
        const _Float16* rp = &tile[(yr + dy) * 136 + xc];
        const f16x8 v0 = *(const f16x8*)&rp[0];
        const f16x8 v1 = *(const f16x8*)&rp[8];
        const f16x8 v2 = *(const f16x8*)&rp[16];
        const f16x8 v3 = *(const f16x8*)&rp[24];
        float rv[18];
        #pragma unroll
        for (int i = 0; i < 18; ++i) {
            const int idx = 7 + i;    // LDS cols xc+7 .. xc+24 = global cols xc-1 .. xc+16
            const _Float16 h = (idx < 8)  ? v0[idx]
                             : (idx < 16) ? v1[idx - 8]
                             : (idx < 24) ? v2[idx - 16]
                                          : v3[idx - 24];
            rv[i] = (float)h;
        }
        const float w0 = w[dy * 3 + 0], w1 = w[dy * 3 + 1], w2 = w[dy * 3 + 2];
        #pragma unroll
        for (int c = 0; c < 16; ++c) {
            acc[c] = fmaf(rv[c],     w0, acc[c]);
            acc[c] = fmaf(rv[c + 1], w1, acc[c]);
            acc[c] = fmaf(rv[c + 2], w2, acc[c]);
        }
    }

    alignas(16) _Float16 oh[16];
    float ssum = 0.f;
    #pragma unroll
    for (int c = 0; c < 16; ++c) {
        oh[c] = (_Float16)acc[c];
        ssum = fmaf(acc[c], acc[c], ssum);
    }
    _Float16* op = out + (size_t)p * HW + (r0 + yr) * 128 + xc;
    *(f16x8*)&op[0] = *(const f16x8*)&oh[0];
    *(f16x8*)&op[8] = *(const f16x8*)&oh[8];

    if (ss != nullptr) {
        __syncthreads();                   // all tile reads done; reuse LDS
        float* red = (float*)tile;
        red[t] = ssum;
        __syncthreads();
        for (int s = 128; s > 0; s >>= 1) {
            if (t < s) red[t] += red[t + s];
            __syncthreads();
        }
        if (t == 0) atomicAdd(&ss[b * (2 * DIM) + ss_off + cl], red[0]);
    }
}

// ------------- raw gram G[b,h,c,d] = sum_n q[c,n]*k[d,n], fp16 in, atomic fp32 partials -------------
#define GCH 512
__global__ __launch_bounds__(256) void gram_qk(
    const _Float16* __restrict__ qA, const _Float16* __restrict__ kA,
    float* __restrict__ G)
{
    const int n0 = blockIdx.x * GCH;
    const int h  = blockIdx.y;
    const int b  = blockIdx.z;
    const _Float16* qb = qA + ((size_t)b * DIM + h * CPH) * HW;
    const _Float16* kb = kA + ((size_t)b * DIM + h * CPH) * HW;

    __shared__ float qs[CPH][132];
    __shared__ float ks[CPH][132];

    const int t  = threadIdx.x;
    const int tx = t & 15, ty = t >> 4;
    float acc[3][3] = {{0.f,0.f,0.f},{0.f,0.f,0.f},{0.f,0.f,0.f}};

    for (int sc = 0; sc < GCH; sc += 128) {
        __syncthreads();
        #pragma unroll
        for (int i = 0; i < 6; ++i) {
            const int idx = t + i * 256;
            const int row = idx >> 5, col = (idx & 31) << 2;
            const size_t g = (size_t)row * HW + n0 + sc + col;
            const f16x4 qv = *(const f16x4*)&qb[g];
            const f16x4 kv = *(const f16x4*)&kb[g];
            *(float4*)&qs[row][col] = make_float4((float)qv[0], (float)qv[1],
                                                  (float)qv[2], (float)qv[3]);
            *(float4*)&ks[row][col] = make_float4((float)kv[0], (float)kv[1],
                                                  (float)kv[2], (float)kv[3]);
        }
        __syncthreads();
        for (int jj = 0; jj < 128; jj += 4) {
            float qv[3][4], kv[3][4];
            #pragma unroll
            for (int i = 0; i < 3; ++i) {
                const float4 tq = *(const float4*)&qs[ty * 3 + i][jj];
                qv[i][0] = tq.x; qv[i][1] = tq.y; qv[i][2] = tq.z; qv[i][3] = tq.w;
                const float4 tk = *(const float4*)&ks[tx * 3 + i][jj];
                kv[i][0] = tk.x; kv[i][1] = tk.y; kv[i][2] = tk.z; kv[i][3] = tk.w;
            }
            #pragma unroll
            for (int i = 0; i < 3; ++i)
                #pragma unroll
                for (int jk = 0; jk < 3; ++jk)
                    acc[i][jk] += qv[i][0]*kv[jk][0] + qv[i][1]*kv[jk][1]
                                + qv[i][2]*kv[jk][2] + qv[i][3]*kv[jk][3];
        }
    }

    float* Gp = G + ((size_t)(b * NHEADS + h)) * CPH * CPH;
    #pragma unroll
    for (int i = 0; i < 3; ++i)
        #pragma unroll
        for (int jk = 0; jk < 3; ++jk)
            atomicAdd(&Gp[(ty * 3 + i) * CPH + tx * 3 + jk], acc[i][jk]);
}

// ------------- normalize + 4x top-k softmax combined into one P (one wave per row) -------------
__global__ __launch_bounds__(64) void topk_combine(
    const float* __restrict__ G, const float* __restrict__ ss,
    const float* __restrict__ temp,
    const float* __restrict__ a1, const float* __restrict__ a2,
    const float* __restrict__ a3, const float* __restrict__ a4,
    float* __restrict__ P)
{
    const int row = blockIdx.x;           // bh*48 + r
    const int bh  = row / CPH;
    const int r   = row - bh * CPH;
    const int b = bh >> 3, h = bh & 7;
    const int l = threadIdx.x;

    const float tpr = temp[h];
    const float* ssb = ss + b * (2 * DIM);
    const float invq = 1.f / sqrtf(ssb[h * CPH + r]);

    float att = -3.0e38f;
    if (l < CPH)
        att = G[(size_t)row * CPH + l] * invq * (1.f / sqrtf(ssb[DIM + h * CPH + l])) * tpr;

    int cnt = 0;                          // # strictly greater
    #pragma unroll
    for (int i = 0; i < CPH; ++i)
        cnt += (__shfl(att, i) > att) ? 1 : 0;

    const float mx   = wave_max(att);
    const float thr0 = wave_min((l < CPH && cnt < 24) ? att : 3.0e38f);
    const float thr1 = wave_min((l < CPH && cnt < 32) ? att : 3.0e38f);
    const float thr2 = wave_min((l < CPH && cnt < 36) ? att : 3.0e38f);
    const float thr3 = wave_min((l < CPH && cnt < 38) ? att : 3.0e38f);

    const float e = (l < CPH) ? expf(att - mx) : 0.f;
    const float Z0 = wave_sum(att >= thr0 ? e : 0.f);
    const float Z1 = wave_sum(att >= thr1 ? e : 0.f);
    const float Z2 = wave_sum(att >= thr2 ? e : 0.f);
    const float Z3 = wave_sum(att >= thr3 ? e : 0.f);

    const float w0 = a1[0] / Z0, w1 = a2[0] / Z1, w2 = a3[0] / Z2, w3 = a4[0] / Z3;
    float pv = 0.f;
    if (att >= thr0) pv += w0 * e;
    if (att >= thr1) pv += w1 * e;
    if (att >= thr2) pv += w2 * e;
    if (att >= thr3) pv += w3 * e;
    if (l < CPH) P[(size_t)row * CPH + l] = pv;
}

// ------------- out1t[b][n][h*48+c] = sum_d P[b,h,c,d] * v[b,h,d,n], fp16 io -------------
__global__ __launch_bounds__(256) void pv_apply(
    const _Float16* __restrict__ v, const float* __restrict__ P,
    _Float16* __restrict__ out1t)
{
    const int bh = blockIdx.y;
    const int b = bh >> 3, h = bh & 7;
    const int n0 = blockIdx.x * 256;

    __shared__ float sPT[CPH][52];            // [d][c]
    __shared__ __align__(16) _Float16 sO[256 * 48];  // [n_local][c]
    const int t = threadIdx.x;
    for (int i = t; i < CPH * CPH; i += 256) {
        const int c = i / CPH, d = i % CPH;
        sPT[d][c] = P[(size_t)bh * CPH * CPH + i];
    }
    __syncthreads();

    const int cg = t >> 6;
    const int lane = t & 63;
    const _Float16* vb = v + ((size_t)b * DIM + h * CPH) * HW + n0 + lane * 4;

    float acc[12][4];
    #pragma unroll
    for (int i = 0; i < 12; ++i)
        #pragma unroll
        for (int jn = 0; jn < 4; ++jn) acc[i][jn] = 0.f;

    for (int d = 0; d < CPH; ++d) {
        const f16x4 vv = *(const f16x4*)&vb[(size_t)d * HW];
        const float vvs[4] = {(float)vv[0], (float)vv[1], (float)vv[2], (float)vv[3]};
        #pragma unroll
        for (int cq = 0; cq < 3; ++cq) {
            const float4 pc = *(const float4*)&sPT[d][cg * 12 + cq * 4];
            const float pcs[4] = {pc.x, pc.y, pc.z, pc.w};
            #pragma unroll
            for (int a = 0; a < 4; ++a)
                #pragma unroll
                for (int jn = 0; jn < 4; ++jn)
                    acc[cq * 4 + a][jn] = fmaf(pcs[a], vvs[jn], acc[cq * 4 + a][jn]);
        }
    }

    #pragma unroll
    for (int jn = 0; jn < 4; ++jn)
        #pragma unroll
        for (int cq = 0; cq < 3; ++cq)
            #pragma unroll
            for (int a = 0; a < 4; ++a)
                sO[(lane * 4 + jn) * 48 + cg * 12 + cq * 4 + a]
                    = (_Float16)acc[cq * 4 + a][jn];
    __syncthreads();

    _Float16* dst = out1t + ((size_t)b * HW + n0 + t) * DIM + h * CPH;
    #pragma unroll
    for (int i = 0; i < 6; ++i)
        *(f16x8*)&dst[i * 8] = *(const f16x8*)&sO[t * 48 + i * 8];
}

extern "C" void kernel_launch(void* const* d_in, const int* in_sizes, int n_in,
                              void* d_out, int out_size, void* d_ws, size_t ws_size,
                              hipStream_t stream)
{
    const float* x      = (const float*)d_in[0];
    const float* qkv_w  = (const float*)d_in[1];
    const float* dw_w   = (const float*)d_in[2];
    const float* proj_w = (const float*)d_in[3];
    const float* temp   = (const float*)d_in[4];
    const float* a1 = (const float*)d_in[5];
    const float* a2 = (const float*)d_in[6];
    const float* a3 = (const float*)d_in[7];
    const float* a4 = (const float*)d_in[8];
    float* out = (float*)d_out;

    const size_t PBE = (size_t)HW * DIM;        // per-batch elems (6,291,456)
    const size_t WQE = (size_t)1152 * 384;
    const size_t WPE = (size_t)384 * 384;

    // 4 fp16 regions (A=xt->out1t, C=raw, D=q~->v~, E=k~) + fp16 weights + fp32 small
    auto need_for = [&](size_t nb) -> size_t {
        return nb * PBE * 2 * 4 + (WQE + WPE) * 2
             + (nb * 768 + 2 * nb * NHEADS * CPH * CPH) * 4;
    };

    int nb, npass;
    if      (ws_size >= need_for(4)) { nb = 4; npass = 1; }
    else if (ws_size >= need_for(2)) { nb = 2; npass = 2; }
    else if (ws_size >= need_for(1)) { nb = 1; npass = 4; }
    else return;

    _Float16* A  = (_Float16*)d_ws;             // xt -> out1t [nb][HW][384]
    _Float16* C  = A + (size_t)nb * PBE;        // raw qkv group [nb][384][HW]
    _Float16* D  = C + (size_t)nb * PBE;        // q~ -> v~
    _Float16* E  = D + (size_t)nb * PBE;        // k~
    _Float16* wq = E + (size_t)nb * PBE;        // qkv_w fp16 [1152][384]
    _Float16* wp = wq + WQE;                    // proj_w fp16 [384][384]
    float* buf_ss = (float*)(wp + WPE);                       // [nb][768]
    float* buf_G  = buf_ss + (size_t)nb * 768;                // [nb][8][48][48]
    float* buf_P  = buf_G + (size_t)nb * NHEADS * CPH * CPH;

    cvt_w<<<dim3((1152 * 384 + 255) / 256), 256, 0, stream>>>(qkv_w, wq, 1152 * 384);
    cvt_w<<<dim3((384 * 384 + 255) / 256), 256, 0, stream>>>(proj_w, wp, 384 * 384);

    for (int p = 0; p < npass; ++p) {
        const int b0 = p * nb;
        const float* xp   = x   + (size_t)b0 * PBE;
        float*       outp = out + (size_t)b0 * PBE;

        const dim3 ggrid(HW / 128, DIM / 128, nb);
        const dim3 dgrid(nb * DIM * 4);

        transpose_cvt<<<dim3(HW / 256, DIM / 16, nb), 256, 0, stream>>>(xp, A);
        // zero ss + G (contiguous) — dwconv and gram accumulate atomically
        hipMemsetAsync(buf_ss, 0,
                       ((size_t)nb * 768 + (size_t)nb * NHEADS * CPH * CPH) * sizeof(float),
                       stream);

        // q path: GEMM -> C (fp16), dwconv+ss -> D
        gemm_f16<<<ggrid, 256, 0, stream>>>(wq, A, C, 0);
        dwconv_f16<<<dgrid, 256, 0, stream>>>(C, dw_w, D, buf_ss, 0);
        // k path: GEMM -> C, dwconv+ss -> E
        gemm_f16<<<ggrid, 256, 0, stream>>>(wq + (size_t)DIM * DIM, A, C, 0);
        dwconv_f16<<<dgrid, 256, 0, stream>>>(C, dw_w + (size_t)DIM * 9, E, buf_ss, DIM);

        gram_qk<<<dim3(HW / GCH, NHEADS, nb), 256, 0, stream>>>(D, E, buf_G);
        topk_combine<<<dim3(nb * NHEADS * CPH), 64, 0, stream>>>(
            buf_G, buf_ss, temp, a1, a2, a3, a4, buf_P);

        // v path: GEMM -> C, dwconv -> D (q~ dead after gram)
        gemm_f16<<<ggrid, 256, 0, stream>>>(wq + (size_t)2 * DIM * DIM, A, C, 0);
        dwconv_f16<<<dgrid, 256, 0, stream>>>(C, dw_w + (size_t)2 * DIM * 9, D, nullptr, 0);

        // out1^T -> A (xt dead after v GEMM)
        pv_apply<<<dim3(HW / 256, nb * NHEADS), 256, 0, stream>>>(D, buf_P, A);

        // proj: fp16 GEMM -> fp32 out
        gemm_f16<<<ggrid, 256, 0, stream>>>(wp, A, outp, 1);
    }
}